// Round 1
// baseline (6538.845 us; speedup 1.0000x reference)
//
#include <hip/hip_runtime.h>
#include <hip/hip_fp16.h>
#include <math.h>

#define NB 8
#define CI 64
#define CO 128
#define HW 96
#define PATCH 16
#define NP 6
#define NE 8
#define NFREQ 8
#define OHW 98

typedef __attribute__((ext_vector_type(8))) unsigned short ushort8v;

// LDS layout (dynamic):
//   xs   : CI*18*18 f16        = 41472 B
//   combs: CO*256   f16        = 65536 B
#define XS_ELEMS (CI * 18 * 18)
#define LDS_BYTES (XS_ELEMS * 2 + CO * 256 * 2)

__global__ __launch_bounds__(256) void pce_main(
    const float* __restrict__ x,    // [8,64,96,96]
    const float* __restrict__ ew,   // [8,128,64,3,3]
    const float* __restrict__ eb,   // [8,128]
    const float* __restrict__ rw,   // [8,32]
    const float* __restrict__ rb,   // [8]
    const float* __restrict__ fw,   // [128,128]
    const float* __restrict__ fb,   // [128]
    const float* __restrict__ thrp, // [1]
    float* __restrict__ out)        // [8,128,98,98]
{
    extern __shared__ char smem[];
    unsigned short* xs    = (unsigned short*)smem;
    unsigned short* combs = (unsigned short*)(smem + XS_ELEMS * 2);

    const int tid = threadIdx.x;
    const int bid = blockIdx.x;
    const int b  = bid / (NP * NP);
    const int py = (bid % (NP * NP)) / NP;
    const int px = bid % NP;

    // ---- stage x halo (18x18 per ci) into LDS as f16 ----
    const int h0 = py * PATCH - 1;
    const int w0 = px * PATCH - 1;
    for (int i = tid; i < XS_ELEMS; i += 256) {
        int ci = i / 324;
        int r  = (i % 324) / 18;
        int c  = i % 18;
        int gy = h0 + r;
        int gx = w0 + c;
        float v = 0.0f;
        if ((unsigned)gy < (unsigned)HW && (unsigned)gx < (unsigned)HW)
            v = x[((b * CI + ci) * HW + gy) * HW + gx];
        xs[i] = __half_as_ushort(__float2half(v));
    }

    // ---- compute gates for this patch (redundant per thread, then uniform) ----
    float gate[NE];
    {
        const float PI_F = 3.14159265358979323846f;
        float fy[16], fxv[16];
        float pyc = ((float)py + 0.5f) / (float)NP;
        float pxc = ((float)px + 0.5f) / (float)NP;
#pragma unroll
        for (int k = 0; k < NFREQ; ++k) {
            float fr = (float)(1 << k) * PI_F;
            float ay = pyc * fr;
            float ax = pxc * fr;
            fy[k]         = sinf(ay);
            fy[k + NFREQ] = cosf(ay);
            fxv[k]         = sinf(ax);
            fxv[k + NFREQ] = cosf(ax);
        }
        float thr = thrp[0];
#pragma unroll
        for (int e = 0; e < NE; ++e) {
            float l = rb[e];
#pragma unroll
            for (int f = 0; f < 16; ++f) l = fmaf(fy[f],  rw[e * 32 + f],      l);
#pragma unroll
            for (int f = 0; f < 16; ++f) l = fmaf(fxv[f], rw[e * 32 + 16 + f], l);
            float g = 1.0f / (1.0f + expf(-l));
            g = (g > thr) ? g : 0.0f;
            gate[e] = __uint_as_float(
                (unsigned)__builtin_amdgcn_readfirstlane((int)__float_as_uint(g)));
        }
    }

    __syncthreads();

    const int ty = tid >> 4;   // 0..15 (pixel row in patch)
    const int tx = tid & 15;   // 0..15 (pixel col in patch)

    // ---- phase 1: gated expert 3x3 convs -> combined (LDS, f16) ----
    for (int cc = 0; cc < CO; cc += 32) {
        float comb[32];
#pragma unroll
        for (int c = 0; c < 32; ++c) comb[c] = 0.0f;

#pragma unroll 1
        for (int e = 0; e < NE; ++e) {
            float g = gate[e];
            if (g == 0.0f) continue;

            float cacc[32];
#pragma unroll
            for (int c = 0; c < 32; ++c) cacc[c] = eb[e * CO + cc + c];

#pragma unroll 1
            for (int ci = 0; ci < CI; ++ci) {
                float xw[9];
#pragma unroll
                for (int ky = 0; ky < 3; ++ky)
#pragma unroll
                    for (int kx = 0; kx < 3; ++kx)
                        xw[ky * 3 + kx] = __half2float(__ushort_as_half(
                            xs[(ci * 18 + ty + ky) * 18 + (tx + kx)]));

                const float* wp = ew + (size_t)(((e * CO + cc) * CI) + ci) * 9;
#pragma unroll
                for (int c = 0; c < 32; ++c) {
#pragma unroll
                    for (int k = 0; k < 9; ++k)
                        cacc[c] = fmaf(xw[k], wp[c * (CI * 9) + k], cacc[c]);
                }
            }
#pragma unroll
            for (int c = 0; c < 32; ++c)
                comb[c] = fmaf(g, fmaxf(cacc[c], 0.0f), comb[c]);
        }

#pragma unroll
        for (int c = 0; c < 32; ++c)
            combs[(cc + c) * 256 + tid] = __half_as_ushort(__float2half(comb[c]));
    }

    __syncthreads();

    // ---- phase 2: 1x1 conv (128x128) from LDS combined, write interior ----
    const int px_tile   = tid & 31;         // 8-pixel group
    const int px0       = px_tile * 8;
    const int co2_base  = (tid >> 5) * 4;   // 0,4,...,28
    const int ty_p      = px0 >> 4;
    const int tx_p0     = px0 & 15;

#pragma unroll 1
    for (int rep = 0; rep < 4; ++rep) {
        int co2_0 = co2_base + rep * 32;
        float acc[4][8];
#pragma unroll
        for (int j = 0; j < 4; ++j)
#pragma unroll
            for (int i = 0; i < 8; ++i) acc[j][i] = 0.0f;

#pragma unroll 1
        for (int c0 = 0; c0 < CO; c0 += 4) {
            float xf[4][8];
#pragma unroll
            for (int cj = 0; cj < 4; ++cj) {
                ushort8v cv = *(const ushort8v*)&combs[(c0 + cj) * 256 + px0];
#pragma unroll
                for (int i = 0; i < 8; ++i)
                    xf[cj][i] = __half2float(__ushort_as_half(cv[i]));
            }
#pragma unroll
            for (int j = 0; j < 4; ++j) {
                const float4 wv = *(const float4*)&fw[(co2_0 + j) * CO + c0];
#pragma unroll
                for (int i = 0; i < 8; ++i) {
                    acc[j][i] = fmaf(wv.x, xf[0][i], acc[j][i]);
                    acc[j][i] = fmaf(wv.y, xf[1][i], acc[j][i]);
                    acc[j][i] = fmaf(wv.z, xf[2][i], acc[j][i]);
                    acc[j][i] = fmaf(wv.w, xf[3][i], acc[j][i]);
                }
            }
        }

#pragma unroll
        for (int j = 0; j < 4; ++j) {
            int co2 = co2_0 + j;
            float bias = fb[co2];
            float* op = out + ((size_t)(b * CO + co2) * OHW + (1 + py * PATCH + ty_p)) * OHW
                            + (1 + px * PATCH + tx_p0);
#pragma unroll
            for (int i = 0; i < 8; ++i) op[i] = acc[j][i] + bias;
        }
    }
}

// fill the 1-pixel border ring (padding=1 on a 1x1 conv -> pure bias)
__global__ __launch_bounds__(256) void pce_border(
    const float* __restrict__ fb, float* __restrict__ out)
{
    int idx = blockIdx.x * 256 + threadIdx.x;
    const int total = NB * CO * 388;
    if (idx >= total) return;
    int seg = idx % 388;
    int bc  = idx / 388;
    int co  = bc % CO;
    int b   = bc / CO;
    int h, w;
    if      (seg < 98)  { h = 0;              w = seg; }
    else if (seg < 196) { h = 97;             w = seg - 98; }
    else if (seg < 292) { h = seg - 196 + 1;  w = 0; }
    else                { h = seg - 292 + 1;  w = 97; }
    out[((size_t)(b * CO + co) * OHW + h) * OHW + w] = fb[co];
}

extern "C" void kernel_launch(void* const* d_in, const int* in_sizes, int n_in,
                              void* d_out, int out_size, void* d_ws, size_t ws_size,
                              hipStream_t stream) {
    const float* x   = (const float*)d_in[0];
    const float* ew  = (const float*)d_in[1];
    const float* eb  = (const float*)d_in[2];
    const float* rw  = (const float*)d_in[3];
    const float* rb  = (const float*)d_in[4];
    const float* fw  = (const float*)d_in[5];
    const float* fb  = (const float*)d_in[6];
    const float* thr = (const float*)d_in[7];
    float* out = (float*)d_out;

    hipLaunchKernelGGL(pce_main, dim3(NB * NP * NP), dim3(256), LDS_BYTES, stream,
                       x, ew, eb, rw, rb, fw, fb, thr, out);

    int nborder = NB * CO * 388;
    hipLaunchKernelGGL(pce_border, dim3((nborder + 255) / 256), dim3(256), 0, stream,
                       fb, out);
}

// Round 2
// 153.666 us; speedup vs baseline: 42.5524x; 42.5524x over previous
//
#include <hip/hip_runtime.h>
#include <hip/hip_fp16.h>
#include <math.h>

// ---------------- problem constants ----------------
#define HW    96
#define OHW   98
#define CI    64
#define COO   128
#define NPCH  36      // 6x6 patches
#define TAPS  9

using f16    = _Float16;
using f16x8  = __attribute__((ext_vector_type(8))) _Float16;
using f32x16 = __attribute__((ext_vector_type(16))) float;

// ---------------- workspace layout (bytes) ----------------
// ewT : [8][9][128 co][64 ci] f16            = 1179648
// fw16: [128 co2][128 co] f16                = 32768
// comb: [8][36 patch][256 pxl][128 co] f16   = 18874368  (co-chunks XOR-swizzled by pxl&15)
#define EWT_OFF   0
#define FW_OFF    1179648
#define COMB_OFF  1212416

__device__ __forceinline__ void gl_lds16(const void* g, void* l) {
  __builtin_amdgcn_global_load_lds(
      (const __attribute__((address_space(1))) unsigned int*)g,
      (__attribute__((address_space(3))) unsigned int*)l, 16, 0, 0);
}

// ============ K0: weight transpose/convert ============
// ewT[e][tap][co][ci] f16 from ew[e][co][ci][ky][kx] f32 ; fw16[co2][co] f16
__global__ __launch_bounds__(256) void pce_prep(
    const float* __restrict__ ew, const float* __restrict__ fw, char* __restrict__ ws)
{
  int i = blockIdx.x * 256 + threadIdx.x;
  if (i < 73728) {                      // 72*128*8 chunks of 8 f16
    int pos = i & 7;
    int co  = (i >> 3) & 127;
    int t   = i >> 10;                  // e*9+tap
    int e = t / 9, tap = t - e * 9;
    int ci0 = pos * 8;
    const float* s = ew + ((size_t)((e * 128 + co) * 64 + ci0)) * 9 + tap;
    f16x8 v;
#pragma unroll
    for (int j = 0; j < 8; ++j) v[j] = (f16)s[j * 9];
    *(f16x8*)(ws + EWT_OFF + (size_t)i * 16) = v;
  } else if (i < 73728 + 2048) {        // fw16
    int j = i - 73728;
    int pos = j & 15, co2 = j >> 4;
    const float* s = fw + co2 * 128 + pos * 8;
    f16x8 v;
#pragma unroll
    for (int k = 0; k < 8; ++k) v[k] = (f16)s[k];
    *(f16x8*)(ws + FW_OFF + (size_t)j * 16) = v;
  }
}

// ============ K1: gated expert 3x3 convs -> comb (f16, ws) ============
// block = (b, patch). 256 thr = 4 waves. GEMM per expert: M=128 co, N=256 px, K=64ci x 9taps
// LDS: xs [18r][18c][64ci swz] f16 = 41472 | Wtap [128co][64ci swz] f16 = 16384 | gates 32
__global__ __launch_bounds__(256, 2) void pce_expert(
    const float* __restrict__ x, const float* __restrict__ eb,
    const float* __restrict__ rw, const float* __restrict__ rb,
    const float* __restrict__ thrp, char* ws)
{
  __shared__ char sm[57920];
  const int tid = threadIdx.x;
  const int blk = blockIdx.x;
  const int b = blk / 36, patch = blk - b * 36;
  const int py = patch / 6, px = patch - py * 6;

  // ---- stage x halo -> xs f16, chunk-swizzled: pos = (ci>>3) ^ (c&7) ----
#pragma unroll 1
  for (int ch = tid; ch < 2592; ch += 256) {
    int pos = ch & 7, p = ch >> 3;
    int r = p / 18, c = p - r * 18;
    int c8 = pos ^ (c & 7);
    int gy = py * 16 + r - 1, gx = px * 16 + c - 1;
    f16x8 v;
#pragma unroll
    for (int j = 0; j < 8; ++j) v[j] = (f16)0.f;
    if ((unsigned)gy < 96u && (unsigned)gx < 96u) {
      const float* xp = x + ((size_t)(b * 64 + c8 * 8) * 96 + gy) * 96 + gx;
#pragma unroll
      for (int j = 0; j < 8; ++j) v[j] = (f16)xp[(size_t)j * 9216];
    }
    *(f16x8*)(sm + p * 128 + pos * 16) = v;
  }

  // ---- gates (uniform) ----
  int mask_s;
  {
    float sy[8], cy[8], sx[8], cx[8];
    float pyc = ((float)py + 0.5f) * (1.f / 6.f);
    float pxc = ((float)px + 0.5f) * (1.f / 6.f);
#pragma unroll
    for (int k = 0; k < 8; ++k) {
      float fr = (float)(1 << k) * 3.14159265358979323846f;
      sy[k] = sinf(pyc * fr); cy[k] = cosf(pyc * fr);
      sx[k] = sinf(pxc * fr); cx[k] = cosf(pxc * fr);
    }
    float thr = thrp[0];
    unsigned m = 0;
#pragma unroll
    for (int e = 0; e < 8; ++e) {
      float l = rb[e];
#pragma unroll
      for (int k = 0; k < 8; ++k) {
        l = fmaf(sy[k], rw[e * 32 + k],      l);
        l = fmaf(cy[k], rw[e * 32 + 8 + k],  l);
        l = fmaf(sx[k], rw[e * 32 + 16 + k], l);
        l = fmaf(cx[k], rw[e * 32 + 24 + k], l);
      }
      float g = 1.f / (1.f + expf(-l));
      g = (g > thr) ? g : 0.f;
      ((float*)(sm + 57856))[e] = g;
      m |= (g != 0.f ? 1u : 0u) << e;
    }
    mask_s = __builtin_amdgcn_readfirstlane((int)m);
  }

  // ---- W staging LDS addresses (pos = (q&7) ^ (co&7)) ----
  int waddr[4];
#pragma unroll
  for (int it = 0; it < 4; ++it) {
    int q = tid + it * 256;
    int co = q >> 3, pos = (q & 7) ^ (co & 7);
    waddr[it] = 41472 + co * 128 + pos * 16;
  }

  uint4 wreg[4];
  int first = mask_s ? (int)__builtin_ctz((unsigned)mask_s) : -1;
  if (first >= 0) {
    const char* s = ws + EWT_OFF + (size_t)(first * 9) * 16384;
#pragma unroll
    for (int it = 0; it < 4; ++it)
      wreg[it] = *(const uint4*)(s + tid * 16 + it * 4096);
  }

  const int lane = tid & 63, wv = tid >> 6;
  const int l31 = lane & 31, l5 = lane >> 5;
  const int m0 = (wv >> 1) * 64;          // co base   (2 m-tiles of 32)
  const int n0 = (wv & 1) * 128;          // pxl base  (4 n-tiles of 32)
  const int swa = l31 & 7, tx = l31 & 15;
  int tyb[4];
#pragma unroll
  for (int ni = 0; ni < 4; ++ni) tyb[ni] = ((n0 + ni * 32) >> 4) + (l31 >> 4);

  __half2 comb[2][4][8];
#pragma unroll
  for (int mi = 0; mi < 2; ++mi)
#pragma unroll
    for (int ni = 0; ni < 4; ++ni)
#pragma unroll
      for (int h = 0; h < 8; ++h) comb[mi][ni][h] = __floats2half2_rn(0.f, 0.f);

  __syncthreads();   // xs + gates visible

#pragma unroll 1
  for (int e = 0; e < 8; ++e) {
    if (!((mask_s >> e) & 1)) continue;
    float g = ((const float*)(sm + 57856))[e];
    int nm = (e < 7) ? (mask_s >> (e + 1)) : 0;
    int nxt = nm ? (e + 1 + (int)__builtin_ctz((unsigned)nm)) : -1;

    f32x16 ebv[2];
#pragma unroll
    for (int mi = 0; mi < 2; ++mi)
#pragma unroll
      for (int r = 0; r < 16; ++r)
        ebv[mi][r] = eb[e * 128 + m0 + mi * 32 + (r & 3) + 8 * (r >> 2) + 4 * l5];

    f32x16 acc[2][4];
#pragma unroll
    for (int mi = 0; mi < 2; ++mi)
#pragma unroll
      for (int ni = 0; ni < 4; ++ni) acc[mi][ni] = ebv[mi];

#pragma unroll 1
    for (int tap = 0; tap < 9; ++tap) {
      __syncthreads();                      // prior reads of W buffer done
#pragma unroll
      for (int it = 0; it < 4; ++it) *(uint4*)(sm + waddr[it]) = wreg[it];
      if (tap < 8 || nxt >= 0) {            // prefetch next tap / next expert (T14)
        int stp = (tap < 8) ? (e * 9 + tap + 1) : (nxt * 9);
        const char* s = ws + EWT_OFF + (size_t)stp * 16384;
#pragma unroll
        for (int it = 0; it < 4; ++it)
          wreg[it] = *(const uint4*)(s + tid * 16 + it * 4096);
      }
      __syncthreads();                      // W buffer ready
      const int ky = tap / 3, kx = tap - ky * 3;
      const int swb = (tx + kx) & 7;
#pragma unroll
      for (int ks = 0; ks < 4; ++ks) {
        f16x8 av[2], bv[4];
#pragma unroll
        for (int mi = 0; mi < 2; ++mi)
          av[mi] = *(const f16x8*)(sm + 41472 + (m0 + mi * 32 + l31) * 128
                                   + ((((ks << 1) | l5) ^ swa) << 4));
#pragma unroll
        for (int ni = 0; ni < 4; ++ni)
          bv[ni] = *(const f16x8*)(sm + ((tyb[ni] + ky) * 18 + tx + kx) * 128
                                   + ((((ks << 1) | l5) ^ swb) << 4));
#pragma unroll
        for (int mi = 0; mi < 2; ++mi)
#pragma unroll
          for (int ni = 0; ni < 4; ++ni)
            acc[mi][ni] = __builtin_amdgcn_mfma_f32_32x32x16_f16(av[mi], bv[ni], acc[mi][ni], 0, 0, 0);
      }
    }

    __half2 g2 = __floats2half2_rn(g, g);
#pragma unroll
    for (int mi = 0; mi < 2; ++mi)
#pragma unroll
      for (int ni = 0; ni < 4; ++ni)
#pragma unroll
        for (int h = 0; h < 8; ++h) {
          float v0 = fmaxf(acc[mi][ni][2 * h],     0.f);
          float v1 = fmaxf(acc[mi][ni][2 * h + 1], 0.f);
          comb[mi][ni][h] = __hfma2(g2, __floats2half2_rn(v0, v1), comb[mi][ni][h]);
        }
  }

  // ---- store comb (pre-swizzled: chunk pos = (co>>3) ^ (pxl&15)) ----
  char* cb = ws + COMB_OFF + ((size_t)(b * 36 + patch) * 256) * 256;
#pragma unroll
  for (int mi = 0; mi < 2; ++mi)
#pragma unroll
    for (int ni = 0; ni < 4; ++ni) {
      int pxl = n0 + ni * 32 + l31;
      int sw = pxl & 15;
      char* rowp = cb + (size_t)pxl * 256;
#pragma unroll
      for (int q = 0; q < 4; ++q) {
        int co = m0 + mi * 32 + 8 * q + 4 * l5;
        int off = (((co >> 3) ^ sw) << 4) + (co & 7) * 2;
        uint2 u;
        u.x = *(unsigned*)&comb[mi][ni][2 * q];
        u.y = *(unsigned*)&comb[mi][ni][2 * q + 1];
        *(uint2*)(rowp + off) = u;
      }
    }
}

// ============ K2: 1x1 conv (128->128) + bias, interior write ============
// block = (b, patch-half): M=128 pxl, N=128 co2, K=128 co. LDS: comb tile 32KB.
__global__ __launch_bounds__(256, 4) void pce_final(
    const char* __restrict__ ws, const float* __restrict__ fb, float* __restrict__ out)
{
  __shared__ char sm[32768];
  const int tid = threadIdx.x, blk = blockIdx.x;
  const int b = blk / 72, ph = blk - b * 72;
  const int patch = ph >> 1, h = ph & 1;
  const int py = patch / 6, px = patch - py * 6;
  const int lane = tid & 63, wv = tid >> 6;

  const char* csrc = ws + COMB_OFF + (size_t)((b * 36 + patch) * 256 + h * 128) * 256;
#pragma unroll
  for (int it = 0; it < 8; ++it) {
    int off = it * 4096 + wv * 1024;
    gl_lds16(csrc + off + lane * 16, sm + off);
  }

  const int l31 = lane & 31, l5 = lane >> 5;
  const int m0 = (wv >> 1) * 64, n0 = (wv & 1) * 64;

  f32x16 acc[2][2];
#pragma unroll
  for (int mi = 0; mi < 2; ++mi)
#pragma unroll
    for (int ni = 0; ni < 2; ++ni)
#pragma unroll
      for (int r = 0; r < 16; ++r) acc[mi][ni][r] = 0.f;

  __syncthreads();

  const char* fwp = ws + FW_OFF;
#pragma unroll
  for (int ks = 0; ks < 8; ++ks) {
    f16x8 av[2], bv[2];
#pragma unroll
    for (int mi = 0; mi < 2; ++mi) {
      int pxl = m0 + mi * 32 + l31;
      av[mi] = *(const f16x8*)(sm + pxl * 256 + ((((ks << 1) | l5) ^ (pxl & 15)) << 4));
    }
#pragma unroll
    for (int ni = 0; ni < 2; ++ni) {
      int co2 = n0 + ni * 32 + l31;
      bv[ni] = *(const f16x8*)(fwp + co2 * 256 + (((ks << 1) | l5) << 4));
    }
#pragma unroll
    for (int mi = 0; mi < 2; ++mi)
#pragma unroll
      for (int ni = 0; ni < 2; ++ni)
        acc[mi][ni] = __builtin_amdgcn_mfma_f32_32x32x16_f16(av[mi], bv[ni], acc[mi][ni], 0, 0, 0);
  }

#pragma unroll
  for (int mi = 0; mi < 2; ++mi)
#pragma unroll
    for (int ni = 0; ni < 2; ++ni) {
      int co2 = n0 + ni * 32 + l31;
      float bias = fb[co2];
      float* obase = out + (size_t)(b * 128 + co2) * 98 * 98;
#pragma unroll
      for (int q = 0; q < 4; ++q) {
        int pxl = m0 + mi * 32 + 8 * q + 4 * l5;
        int y = py * 16 + h * 8 + (pxl >> 4) + 1;
        int xg = px * 16 + (pxl & 15) + 1;
        float4 vv = make_float4(acc[mi][ni][4 * q + 0] + bias, acc[mi][ni][4 * q + 1] + bias,
                                acc[mi][ni][4 * q + 2] + bias, acc[mi][ni][4 * q + 3] + bias);
        __builtin_memcpy(obase + y * 98 + xg, &vv, 16);
      }
    }
}

// ============ border ring: 1x1 conv with padding=1 -> pure bias ============
__global__ __launch_bounds__(256) void pce_border(
    const float* __restrict__ fb, float* __restrict__ out)
{
  int idx = blockIdx.x * 256 + threadIdx.x;
  const int total = 8 * 128 * 388;
  if (idx >= total) return;
  int seg = idx % 388;
  int bc  = idx / 388;
  int co  = bc % 128;
  int b   = bc / 128;
  int hh, w;
  if      (seg < 98)  { hh = 0;             w = seg; }
  else if (seg < 196) { hh = 97;            w = seg - 98; }
  else if (seg < 292) { hh = seg - 196 + 1; w = 0; }
  else                { hh = seg - 292 + 1; w = 97; }
  out[((size_t)(b * 128 + co) * 98 + hh) * 98 + w] = fb[co];
}

extern "C" void kernel_launch(void* const* d_in, const int* in_sizes, int n_in,
                              void* d_out, int out_size, void* d_ws, size_t ws_size,
                              hipStream_t stream) {
  const float* x   = (const float*)d_in[0];
  const float* ew  = (const float*)d_in[1];
  const float* ebp = (const float*)d_in[2];
  const float* rw  = (const float*)d_in[3];
  const float* rb  = (const float*)d_in[4];
  const float* fw  = (const float*)d_in[5];
  const float* fb  = (const float*)d_in[6];
  const float* thr = (const float*)d_in[7];
  float* out = (float*)d_out;
  char* ws = (char*)d_ws;

  hipLaunchKernelGGL(pce_prep,   dim3(296),  dim3(256), 0, stream, ew, fw, ws);
  hipLaunchKernelGGL(pce_expert, dim3(288),  dim3(256), 0, stream, x, ebp, rw, rb, thr, ws);
  hipLaunchKernelGGL(pce_final,  dim3(576),  dim3(256), 0, stream, ws, fb, out);
  hipLaunchKernelGGL(pce_border, dim3(1552), dim3(256), 0, stream, fb, out);
}